// Round 6
// baseline (270.208 us; speedup 1.0000x reference)
//
#include <hip/hip_runtime.h>

// y = x @ (W * M)^T with M = identity  =>  y[b,d] = x[b,d] * (W[d,d] * M[d,d]).
// Pure HBM-bound elementwise scale: 134 MB read + 134 MB write (~43 us floor
// at the m13-measured 6.29 TB/s float4-copy rate).
//
// Measured ledger (end-to-end; ~169 us is fixed harness poison-fill floor):
//  - r0: 1 float4/thread one-shot, plain stores          -> 237.4 (best)
//  - r2: grid-stride dynamic loop + nt (VGPR=12, serial) -> 258.1
//  - r3: 4 float4/thread at 8 KB stride                  -> 248.1
//  - r4: r0 + nt stores                                  -> 239.4 (neutral)
//  - r5: this kernel -- infra failure, resubmitting unchanged.
//
// r0's wave does ONE 1 KB load then dies -> read-latency coverage relies
// entirely on wave churn (~3.9 TB/s). This version: 8 float4s per thread,
// FULLY UNROLLED straight-line (no loop -> nothing for the compiler to
// serialize, unlike r2), spaced nthreads*4 floats = 16 MB apart (8 fully
// sequential concurrent streams, unlike r3's 8 KB interleave). Each wave
// holds 8 KB of independent reads in flight; 8x fewer wave launches.
//
// Stride = 4,194,304 floats = 2048 whole rows -> the column quad d is
// invariant across all 8 chunks -> ONE diag float4 load per thread.

#define DDIM 2048
#define BDIM 16384

#define NBLK 4096
#define NTHR ((size_t)NBLK * 256)          // 1,048,576 threads
#define STRIDE (NTHR * 4)                  // 4,194,304 floats = 16 MB

typedef float floatx4 __attribute__((ext_vector_type(4)));

// Kernel 1: pull the masked diagonal of W into contiguous workspace.
__global__ void extract_diag_kernel(const float* __restrict__ W,
                                    const float* __restrict__ M,
                                    float* __restrict__ diag) {
    int d = blockIdx.x * blockDim.x + threadIdx.x;
    if (d < DDIM) {
        size_t idx = (size_t)d * (DDIM + 1);
        diag[d] = W[idx] * M[idx];
    }
}

// Kernel 2: out = x * diag[col], 8 float4s per thread in 8 far-strided
// sequential streams, fully unrolled.
__global__ __launch_bounds__(256) void diag_scale8(
    const float* __restrict__ x,
    const float* __restrict__ diag,
    float* __restrict__ out) {
    const size_t t = (size_t)blockIdx.x * blockDim.x + threadIdx.x;
    const size_t i0 = t * 4;
    const int d = (int)(i0 & (DDIM - 1));   // invariant across chunks

    const floatx4 wv = *reinterpret_cast<const floatx4*>(diag + d);

    // 8 independent loads, all issued before any use (straight-line code).
    const floatx4 v0 = *reinterpret_cast<const floatx4*>(x + i0 + 0 * STRIDE);
    const floatx4 v1 = *reinterpret_cast<const floatx4*>(x + i0 + 1 * STRIDE);
    const floatx4 v2 = *reinterpret_cast<const floatx4*>(x + i0 + 2 * STRIDE);
    const floatx4 v3 = *reinterpret_cast<const floatx4*>(x + i0 + 3 * STRIDE);
    const floatx4 v4 = *reinterpret_cast<const floatx4*>(x + i0 + 4 * STRIDE);
    const floatx4 v5 = *reinterpret_cast<const floatx4*>(x + i0 + 5 * STRIDE);
    const floatx4 v6 = *reinterpret_cast<const floatx4*>(x + i0 + 6 * STRIDE);
    const floatx4 v7 = *reinterpret_cast<const floatx4*>(x + i0 + 7 * STRIDE);

    *reinterpret_cast<floatx4*>(out + i0 + 0 * STRIDE) = v0 * wv;
    *reinterpret_cast<floatx4*>(out + i0 + 1 * STRIDE) = v1 * wv;
    *reinterpret_cast<floatx4*>(out + i0 + 2 * STRIDE) = v2 * wv;
    *reinterpret_cast<floatx4*>(out + i0 + 3 * STRIDE) = v3 * wv;
    *reinterpret_cast<floatx4*>(out + i0 + 4 * STRIDE) = v4 * wv;
    *reinterpret_cast<floatx4*>(out + i0 + 5 * STRIDE) = v5 * wv;
    *reinterpret_cast<floatx4*>(out + i0 + 6 * STRIDE) = v6 * wv;
    *reinterpret_cast<floatx4*>(out + i0 + 7 * STRIDE) = v7 * wv;
}

extern "C" void kernel_launch(void* const* d_in, const int* in_sizes, int n_in,
                              void* d_out, int out_size, void* d_ws, size_t ws_size,
                              hipStream_t stream) {
    const float* x = (const float*)d_in[0];
    const float* W = (const float*)d_in[1];
    const float* M = (const float*)d_in[2];
    float* out = (float*)d_out;
    float* diag = (float*)d_ws;  // 2048 floats = 8 KB scratch

    extract_diag_kernel<<<(DDIM + 255) / 256, 256, 0, stream>>>(W, M, diag);

    // 8 chunks x (NTHR threads x 4 floats) = 33,554,432 = BDIM*DDIM exactly.
    diag_scale8<<<NBLK, 256, 0, stream>>>(x, diag, out);
}

// Round 7
// 247.997 us; speedup vs baseline: 1.0896x; 1.0896x over previous
//
#include <hip/hip_runtime.h>

// y = x @ (W * M)^T with M = identity  =>  y[b,d] = x[b,d] * (W[d,d] * M[d,d]).
// Pure HBM-bound elementwise scale: 134 MB read + 134 MB write.
//
// Measured ledger (end-to-end; ~171 us fixed harness floor = 2 poison fills
// + extract_diag + gaps):
//  - r0: 1 f4/thread one-shot (1 dense region/wave)   -> 237.4 (scale ~66 us)
//  - r2: grid-stride serial loop + nt                  -> 258.1
//  - r3: 4 f4/thread, 8 KB stride (4 regions/wave)     -> 248.1
//  - r4: r0 + nt stores                                -> 239.4 (neutral)
//  - r6: 8 f4/thread, 16 MB stride (8 regions/wave)    -> 270.2 (scale ~99 us, 2 TB/s)
//
// Pattern: perf degrades monotonically with REGIONS PER WAVE, not ILP depth
// (poison fills hit 6.6 TB/s at 9.6% occupancy -> in-flight volume is not
// the limiter). This round tests the untried quadrant: deep ILP with ONE
// dense contiguous region per wave. Each wave owns a contiguous 8 KB chunk;
// 8 fully-unrolled dwordx4 loads at chunk + j*1KB + lane*16B. Clean A/B vs
// r6: same depth, same grid, only dense-chunk vs far-strided layout.
//
// Diag index per (j, lane) = j*256 + lane*4 -- identical for every wave and
// block -> the 8 KB diag workspace is L1-resident broadcast.

#define DDIM 2048
#define BDIM 16384

typedef float floatx4 __attribute__((ext_vector_type(4)));

// Kernel 1: pull the masked diagonal of W into contiguous workspace.
__global__ void extract_diag_kernel(const float* __restrict__ W,
                                    const float* __restrict__ M,
                                    float* __restrict__ diag) {
    int d = blockIdx.x * blockDim.x + threadIdx.x;
    if (d < DDIM) {
        size_t idx = (size_t)d * (DDIM + 1);
        diag[d] = W[idx] * M[idx];
    }
}

// Kernel 2: out = x * diag[col]. Each wave: one contiguous 8 KB chunk,
// 8 dense 1 KB load instructions, fully unrolled.
__global__ __launch_bounds__(256) void diag_scale_c8(
    const float* __restrict__ x,
    const float* __restrict__ diag,
    float* __restrict__ out) {
    const int wave = threadIdx.x >> 6;
    const int lane = threadIdx.x & 63;

    // Wave chunk: 2048 floats (8 KB). Block = 4 waves = 32 KB contiguous.
    const size_t base = (size_t)blockIdx.x * 8192 + (size_t)wave * 2048
                      + (size_t)lane * 4;

    // 8 independent dense loads, one region per wave.
    const floatx4 v0 = *reinterpret_cast<const floatx4*>(x + base + 0 * 256);
    const floatx4 v1 = *reinterpret_cast<const floatx4*>(x + base + 1 * 256);
    const floatx4 v2 = *reinterpret_cast<const floatx4*>(x + base + 2 * 256);
    const floatx4 v3 = *reinterpret_cast<const floatx4*>(x + base + 3 * 256);
    const floatx4 v4 = *reinterpret_cast<const floatx4*>(x + base + 4 * 256);
    const floatx4 v5 = *reinterpret_cast<const floatx4*>(x + base + 5 * 256);
    const floatx4 v6 = *reinterpret_cast<const floatx4*>(x + base + 6 * 256);
    const floatx4 v7 = *reinterpret_cast<const floatx4*>(x + base + 7 * 256);

    // Diag float4 per step: d = lane*4 + j*256 (block-invariant, L1-hot).
    const int d0 = lane * 4;
    const floatx4 w0 = *reinterpret_cast<const floatx4*>(diag + d0 + 0 * 256);
    const floatx4 w1 = *reinterpret_cast<const floatx4*>(diag + d0 + 1 * 256);
    const floatx4 w2 = *reinterpret_cast<const floatx4*>(diag + d0 + 2 * 256);
    const floatx4 w3 = *reinterpret_cast<const floatx4*>(diag + d0 + 3 * 256);
    const floatx4 w4 = *reinterpret_cast<const floatx4*>(diag + d0 + 4 * 256);
    const floatx4 w5 = *reinterpret_cast<const floatx4*>(diag + d0 + 5 * 256);
    const floatx4 w6 = *reinterpret_cast<const floatx4*>(diag + d0 + 6 * 256);
    const floatx4 w7 = *reinterpret_cast<const floatx4*>(diag + d0 + 7 * 256);

    *reinterpret_cast<floatx4*>(out + base + 0 * 256) = v0 * w0;
    *reinterpret_cast<floatx4*>(out + base + 1 * 256) = v1 * w1;
    *reinterpret_cast<floatx4*>(out + base + 2 * 256) = v2 * w2;
    *reinterpret_cast<floatx4*>(out + base + 3 * 256) = v3 * w3;
    *reinterpret_cast<floatx4*>(out + base + 4 * 256) = v4 * w4;
    *reinterpret_cast<floatx4*>(out + base + 5 * 256) = v5 * w5;
    *reinterpret_cast<floatx4*>(out + base + 6 * 256) = v6 * w6;
    *reinterpret_cast<floatx4*>(out + base + 7 * 256) = v7 * w7;
}

extern "C" void kernel_launch(void* const* d_in, const int* in_sizes, int n_in,
                              void* d_out, int out_size, void* d_ws, size_t ws_size,
                              hipStream_t stream) {
    const float* x = (const float*)d_in[0];
    const float* W = (const float*)d_in[1];
    const float* M = (const float*)d_in[2];
    float* out = (float*)d_out;
    float* diag = (float*)d_ws;  // 2048 floats = 8 KB scratch

    extract_diag_kernel<<<(DDIM + 255) / 256, 256, 0, stream>>>(W, M, diag);

    // 4096 blocks x 256 thr; each block covers 32 KB contiguous.
    // 4096 * 8192 floats = 33,554,432 = BDIM * DDIM exactly.
    diag_scale_c8<<<4096, 256, 0, stream>>>(x, diag, out);
}

// Round 8
// 238.867 us; speedup vs baseline: 1.1312x; 1.0382x over previous
//
#include <hip/hip_runtime.h>

// y = x @ (W * M)^T where M is the identity mask -> y[b,d] = x[b,d] * W[d,d]*M[d,d].
// Pure HBM-bound elementwise scale: 134 MB read + 134 MB write.
//
// FINAL (restored r0, measured best = 237.4 us end-to-end):
// Exhaustive shape search (r2-r7) all regressed vs this:
//   depth-4 strided (248), depth-8 strided (270), depth-8 dense (248),
//   fused grid-stride loop (258), nt stores (239, neutral).
// ILP depth monotonically HURTS on this stream (compiler caps live loads at
// VGPR~28 anyway); maximal wave churn with one one-shot float4 per thread is
// the fastest read-latency-coverage mechanism measured on this chip.
// Fixed harness floor ~170 us = two 512 MiB poison fills @ 6.6 TB/s + gaps;
// the scale kernel itself runs ~66 us (~201 MB HBM traffic, half of x served
// from Infinity Cache).

#define DDIM 2048
#define BDIM 16384

// Kernel 1: pull the (masked) diagonal of W into contiguous workspace.
// Strided reads (stride D+1 floats) but only 2048 of them -- negligible.
__global__ void extract_diag_kernel(const float* __restrict__ W,
                                    const float* __restrict__ M,
                                    float* __restrict__ diag) {
    int d = blockIdx.x * blockDim.x + threadIdx.x;
    if (d < DDIM) {
        size_t idx = (size_t)d * (DDIM + 1);
        diag[d] = W[idx] * M[idx];
    }
}

// Kernel 2: out[b,d] = x[b,d] * diag[d], float4-vectorized, one float4 per
// thread, fully sequential layout.
__global__ void diag_scale_kernel(const float* __restrict__ x,
                                  const float* __restrict__ diag,
                                  float* __restrict__ out) {
    size_t t = (size_t)blockIdx.x * blockDim.x + threadIdx.x;
    size_t i4 = t * 4;  // flat float index, 4 per thread
    int d = (int)(i4 & (DDIM - 1));  // column index (D power of 2)

    float4 xv = *reinterpret_cast<const float4*>(x + i4);
    float4 wv = *reinterpret_cast<const float4*>(diag + d);

    float4 o;
    o.x = xv.x * wv.x;
    o.y = xv.y * wv.y;
    o.z = xv.z * wv.z;
    o.w = xv.w * wv.w;

    *reinterpret_cast<float4*>(out + i4) = o;
}

extern "C" void kernel_launch(void* const* d_in, const int* in_sizes, int n_in,
                              void* d_out, int out_size, void* d_ws, size_t ws_size,
                              hipStream_t stream) {
    const float* x = (const float*)d_in[0];
    const float* W = (const float*)d_in[1];
    const float* M = (const float*)d_in[2];
    float* out = (float*)d_out;
    float* diag = (float*)d_ws;  // 2048 floats = 8 KB scratch

    // Extract diagonal (one small block-set).
    extract_diag_kernel<<<(DDIM + 255) / 256, 256, 0, stream>>>(W, M, diag);

    // Elementwise scale: B*D/4 float4 lanes.
    const size_t total4 = (size_t)BDIM * DDIM / 4;  // 8,388,608
    const int block = 256;
    const int grid = (int)((total4 + block - 1) / block);  // 32768 blocks
    diag_scale_kernel<<<grid, block, 0, stream>>>(x, diag, out);
}